// Round 10
// baseline (61.869 us; speedup 1.0000x reference)
//
#include <hip/hip_runtime.h>
#include <float.h>
#include <math.h>

#define BB 8
#define HH 256
#define WW 256
#define NPIX 65536          // HH*WW
#define TOT (BB*NPIX)
#define KTOP 80
#define NTIL 64             // 8x8 tiles of 32x32 per image
#define TCAP 128            // max peaks per 32x32 tile (5x5 NMS spacing caps ~121)
#define CAP 8192            // max candidates per batch
#define SELBINS 4096
#define BNDCAP 1024
#define NBLK (BB*NTIL)      // 512
typedef unsigned long long ull;

// ============ fused 9x9 avg-pools -> prod, per-block min/max partials; zero hist+bcnt ============
__global__ void k_box9(const float* __restrict__ vsm, float* __restrict__ prod,
                       float* __restrict__ pmn, float* __restrict__ pmx,
                       unsigned* __restrict__ histg, unsigned* __restrict__ bcnt) {
    int blk = blockIdx.x;
    int b = blk >> 6, t = blk & 63;
    int ty0 = (t >> 3) << 5, tx0 = (t & 7) << 5;
    int tid = threadIdx.x;

    if (tid < 64) histg[b * SELBINS + t * 64 + tid] = 0u;
    if (blk < BB && tid == 0) bcnt[blk] = 0u;

    __shared__ float val[40][40];
    __shared__ float rs_o[40][32];
    __shared__ float rs_m[40][32];
    for (int i = tid; i < 1600; i += 256) {
        int ly = i / 40, lx = i - ly * 40;
        int gy = ty0 - 4 + ly, gx = tx0 - 4 + lx;
        float v = 0.f;
        if (gy >= 0 && gy < HH && gx >= 0 && gx < WW) v = vsm[(b * HH + gy) * WW + gx];
        val[ly][lx] = v;
    }
    __syncthreads();
    for (int i = tid; i < 1280; i += 256) {
        int ly = i >> 5, lx = i & 31;
        float so = 0.f, sm = 0.f;
        #pragma unroll
        for (int d = 0; d < 9; ++d) { float v = val[ly][lx + d]; so += (v > 0.2f) ? 1.f : 0.f; sm += v; }
        rs_o[ly][lx] = so; rs_m[ly][lx] = sm;
    }
    __syncthreads();
    int ox = tid & 31, oy0 = (tid >> 5) << 2;
    float tmn = FLT_MAX, tmx = -FLT_MAX;
    #pragma unroll
    for (int j = 0; j < 4; ++j) {
        int oy = oy0 + j;
        float so = 0.f, sm = 0.f;
        #pragma unroll
        for (int d = 0; d < 9; ++d) { so += rs_o[oy + d][ox]; sm += rs_m[oy + d][ox]; }
        float p = (so * (1.f / 81.f)) * (sm * (1.f / 81.f));
        prod[(b * HH + ty0 + oy) * WW + tx0 + ox] = p;
        tmn = fminf(tmn, p); tmx = fmaxf(tmx, p);
    }
    __shared__ float smn[256], smx[256];
    smn[tid] = tmn; smx[tid] = tmx;
    __syncthreads();
    for (int off = 128; off > 0; off >>= 1) {
        if (tid < off) { smn[tid] = fminf(smn[tid], smn[tid + off]); smx[tid] = fmaxf(smx[tid], smx[tid + off]); }
        __syncthreads();
    }
    if (tid == 0) { pmn[blk] = smn[0]; pmx[blk] = smx[0]; }
}

// ============ score + 5x5 NMS + per-BATCH compact candidates + per-batch histogram ============
__global__ void k_nms(const float* __restrict__ vsm, const float* __restrict__ prod,
                      const float* __restrict__ pmn, const float* __restrict__ pmx,
                      unsigned* __restrict__ bcnt, float* __restrict__ candV,
                      int* __restrict__ candI, unsigned* __restrict__ histg) {
    int blk = blockIdx.x;
    int b = blk >> 6, t = blk & 63;
    int ty0 = (t >> 3) << 5, tx0 = (t & 7) << 5;
    int tid = threadIdx.x;
    __shared__ float sred[2];
    if (tid < 64) {
        float mn = pmn[b * NTIL + tid];
        float mx = pmx[b * NTIL + tid];
        #pragma unroll
        for (int o = 32; o > 0; o >>= 1) { mn = fminf(mn, __shfl_xor(mn, o, 64)); mx = fmaxf(mx, __shfl_xor(mx, o, 64)); }
        if (tid == 0) { sred[0] = mn; sred[1] = mx; }
    }
    __syncthreads();
    float mnp = sred[0];
    float inv = 1.f / (sred[1] - mnp + 1e-6f);
    __shared__ float sc[36][36];
    __shared__ float hm[36][32];
    for (int i = tid; i < 1296; i += 256) {
        int ly = i / 36, lx = i - ly * 36;
        int gy = ty0 - 2 + ly, gx = tx0 - 2 + lx;
        float s = -FLT_MAX;
        if (gy >= 0 && gy < HH && gx >= 0 && gx < WW) {
            int idx = (b * HH + gy) * WW + gx;
            s = vsm[idx] * ((prod[idx] - mnp) * inv);
        }
        sc[ly][lx] = s;
    }
    __syncthreads();
    for (int i = tid; i < 1152; i += 256) {
        int ly = i >> 5, lx = i & 31;
        float m = sc[ly][lx];
        #pragma unroll
        for (int d = 1; d < 5; ++d) m = fmaxf(m, sc[ly][lx + d]);
        hm[ly][lx] = m;
    }
    __syncthreads();
    __shared__ unsigned scnt;
    __shared__ unsigned sbase;
    __shared__ float bv[TCAP];
    __shared__ int bi[TCAP];
    if (tid == 0) scnt = 0;
    __syncthreads();
    int ox = tid & 31, oy0 = (tid >> 5) << 2;
    #pragma unroll
    for (int j = 0; j < 4; ++j) {
        int oy = oy0 + j;
        float m = hm[oy][ox];
        #pragma unroll
        for (int d = 1; d < 5; ++d) m = fmaxf(m, hm[oy + d][ox]);
        float s = sc[oy + 2][ox + 2];
        if (s == m && s > 0.f) {
            unsigned p = atomicAdd(&scnt, 1u);
            if (p < TCAP) { bv[p] = s; bi[p] = (ty0 + oy) * WW + tx0 + ox; }
        }
    }
    __syncthreads();
    unsigned cnt = min(scnt, (unsigned)TCAP);
    if (tid == 0) sbase = cnt ? atomicAdd(&bcnt[b], cnt) : 0u;   // ONE global atomic per tile
    __syncthreads();
    unsigned base = sbase;
    for (unsigned i = tid; i < cnt; i += 256) {
        unsigned pos = base + i;
        if (pos < CAP) {
            float v = bv[i];
            candV[b * CAP + pos] = v;
            candI[b * CAP + pos] = bi[i];
            atomicAdd(&histg[b * SELBINS + (__float_as_uint(v) >> 19)], 1u);
        }
    }
}

// ============ barrier-light exact top-80: wave-shfl hist scan + unsorted accept + wave argmax ============
__global__ void __launch_bounds__(512)
k_topk(const float* __restrict__ depth, const unsigned* __restrict__ bcnt,
       const float* __restrict__ candV, const int* __restrict__ candI,
       const unsigned* __restrict__ histg, float4* __restrict__ pk) {
    int b = blockIdx.x;
    int tid = threadIdx.x;
    int lane = tid & 63;
    int wid = tid >> 6;

    __shared__ unsigned hloc[64][65];   // padded rows: bank = (row + col) % 32 -> 2-way max
    __shared__ ull accS[KTOP];
    __shared__ ull bndS[BNDCAP];
    __shared__ int sB;
    __shared__ unsigned nAccS, nBndS, nTotS;

    // coalesced load of prebuilt histogram into padded LDS
    const unsigned* hg = histg + b * SELBINS;
    for (int i = tid; i < SELBINS; i += 512) hloc[i >> 6][i & 63] = hg[i];
    if (tid == 0) { sB = -1; nAccS = 0; nBndS = 0; nTotS = 0; }
    __syncthreads();                                     // barrier 1

    // wave 0: suffix scan over 4096 bins, entirely via shfl (no barriers)
    if (wid == 0) {
        unsigned part = 0;
        #pragma unroll 8
        for (int j = 0; j < 64; ++j) part += hloc[lane][j];
        unsigned suf = part;                             // inclusive suffix over lanes
        #pragma unroll
        for (int off = 1; off < 64; off <<= 1) {
            unsigned v = __shfl_down(suf, off, 64);
            if (lane + off < 64) suf += v;
        }
        unsigned run = suf - part;                       // suffix over lanes above
        for (int j = 63; j >= 0; --j) {
            unsigned h = hloc[lane][j];
            run += h;                                    // run == suffix(lane*64+j)
            if (run >= KTOP && run - h < KTOP) sB = lane * 64 + j;
        }
    }
    __syncthreads();                                     // barrier 2

    // stream compact candidates (512 threads, ~5 rounds): accept bins>B, stage boundary bin
    int B = sB;
    int nC = min((int)bcnt[b], CAP);
    for (int i = tid; i < nC; i += 512) {
        float v = candV[b * CAP + i];
        unsigned bits = __float_as_uint(v);
        int bin = (int)(bits >> 19);
        if (bin >= B) {
            int id = candI[b * CAP + i];
            ull key = ((ull)bits << 32) | (ull)(0xFFFFFFFFu - (unsigned)id);
            if (bin > B) {
                unsigned p = atomicAdd(&nAccS, 1u);
                if (p < KTOP) accS[p] = key;             // <80 by construction when B>=0
            } else {
                unsigned q = atomicAdd(&nBndS, 1u);
                if (q < BNDCAP) bndS[q] = key;
            }
        }
    }
    __syncthreads();                                     // barrier 3

    // wave 0: fill quota from boundary bin by repeated shfl-argmax (no barriers, exact key order)
    if (wid == 0) {
        unsigned nAcc = min(nAccS, (unsigned)KTOP);
        unsigned nBnd = min(nBndS, (unsigned)BNDCAP);
        unsigned quota = (KTOP > nAcc) ? (KTOP - nAcc) : 0u;
        if (quota > nBnd) quota = nBnd;
        for (unsigned q = 0; q < quota; ++q) {
            ull best = 0ull; int bix = -1;
            for (unsigned i = lane; i < nBnd; i += 64) {
                ull k = bndS[i];
                if (k > best) { best = k; bix = (int)i; }
            }
            #pragma unroll
            for (int off = 32; off > 0; off >>= 1) {     // manual 64-bit shfl reduce
                unsigned blo = (unsigned)best, bhi = (unsigned)(best >> 32);
                unsigned olo = __shfl_xor(blo, off, 64);
                unsigned ohi = __shfl_xor(bhi, off, 64);
                int oix = __shfl_xor(bix, off, 64);
                ull ob = ((ull)ohi << 32) | olo;
                if (ob > best) { best = ob; bix = oix; }
            }
            if (lane == 0) { accS[nAcc + q] = best; bndS[bix] = 0ull; }
        }
        if (lane == 0) nTotS = nAcc + quota;
    }
    __syncthreads();                                     // barrier 4

    // emit packed peak params {log2(val), x, y, c}
    if (tid < KTOP) {
        unsigned nTot = nTotS;
        ull key = ((unsigned)tid < nTot) ? accS[tid] : 0ull;
        float plog = -INFINITY, fx = 0.f, fy = 0.f, c = 0.f;
        if (key) {
            unsigned bits = (unsigned)(key >> 32);
            int idx = (int)(0xFFFFFFFFu - (unsigned)(key & 0xFFFFFFFFu));
            float val = __uint_as_float(bits);
            plog = log2f(val);
            fx = (float)(idx & 255);
            fy = (float)(idx >> 8);
            float z = fmaxf(depth[b * NPIX + idx], 0.001f);
            float r = fminf(fmaxf(14.f / z, 1.5f), 18.f);
            float s2 = 0.36f * r * r;                     // (0.6*r)^2
            c = 1.44269504f / (2.f * s2 + 1e-6f);         // log2(e)/denom
        }
        pk[b * KTOP + tid] = make_float4(plog, fx, fy, c);
    }
}

// ============ log-domain gaussian splat: 4 px/thread, single exp2 per pixel ============
__global__ void k_splat(const float4* __restrict__ pk, float* __restrict__ gauss,
                        float* __restrict__ gmn, float* __restrict__ gmx) {
    int blk = blockIdx.x;
    int b = blk >> 6;
    int y0 = (blk & 63) << 2;
    int x = threadIdx.x;
    __shared__ float4 lp[KTOP];
    if (x < KTOP) lp[x] = pk[b * KTOP + x];
    __syncthreads();
    float fx = (float)x, fy = (float)y0;
    float g0 = -INFINITY, g1 = -INFINITY, g2 = -INFINITY, g3 = -INFINITY;
    #pragma unroll 4
    for (int k = 0; k < KTOP; ++k) {
        float4 q = lp[k];
        float dx = fx - q.y;
        float dx2 = dx * dx;
        float dy = fy - q.z;
        float d2;
        d2 = fmaf(dy, dy, dx2);        g0 = fmaxf(g0, fmaf(-d2, q.w, q.x));
        float dyb = dy + 1.f;
        d2 = fmaf(dyb, dyb, dx2);      g1 = fmaxf(g1, fmaf(-d2, q.w, q.x));
        float dyc = dy + 2.f;
        d2 = fmaf(dyc, dyc, dx2);      g2 = fmaxf(g2, fmaf(-d2, q.w, q.x));
        float dyd = dy + 3.f;
        d2 = fmaf(dyd, dyd, dx2);      g3 = fmaxf(g3, fmaf(-d2, q.w, q.x));
    }
    float v0 = exp2f(g0), v1 = exp2f(g1), v2 = exp2f(g2), v3 = exp2f(g3);
    int base = (b * HH + y0) * WW + x;
    gauss[base] = v0; gauss[base + WW] = v1; gauss[base + 2 * WW] = v2; gauss[base + 3 * WW] = v3;
    float tmn = fminf(fminf(v0, v1), fminf(v2, v3));
    float tmx = fmaxf(fmaxf(v0, v1), fmaxf(v2, v3));
    __shared__ float smn[256], smx[256];
    smn[x] = tmn; smx[x] = tmx;
    __syncthreads();
    for (int off = 128; off > 0; off >>= 1) {
        if (x < off) { smn[x] = fminf(smn[x], smn[x + off]); smx[x] = fmaxf(smx[x], smx[x + off]); }
        __syncthreads();
    }
    if (x == 0) { gmn[blk] = smn[0]; gmx[blk] = smx[0]; }
}

// ============ final norm01 (float4 vectorized) ============
__global__ void k_norm(const float* __restrict__ gauss, const float* __restrict__ gmn,
                       const float* __restrict__ gmx, float* __restrict__ out) {
    int blk = blockIdx.x;
    int b = blk >> 6;
    int tid = threadIdx.x;
    __shared__ float sred[2];
    if (tid < 64) {
        float mn = gmn[b * NTIL + tid];
        float mx = gmx[b * NTIL + tid];
        #pragma unroll
        for (int o = 32; o > 0; o >>= 1) { mn = fminf(mn, __shfl_xor(mn, o, 64)); mx = fmaxf(mx, __shfl_xor(mx, o, 64)); }
        if (tid == 0) { sred[0] = mn; sred[1] = mx; }
    }
    __syncthreads();
    float mn = sred[0];
    float inv = 1.f / (sred[1] - mn + 1e-6f);
    int i = blk * 256 + tid;
    float4 v = ((const float4*)gauss)[i];
    v.x = (v.x - mn) * inv;
    v.y = (v.y - mn) * inv;
    v.z = (v.z - mn) * inv;
    v.w = (v.w - mn) * inv;
    ((float4*)out)[i] = v;
}

extern "C" void kernel_launch(void* const* d_in, const int* in_sizes, int n_in,
                              void* d_out, int out_size, void* d_ws, size_t ws_size,
                              hipStream_t stream) {
    const float* vsm   = (const float*)d_in[0];
    const float* depth = (const float*)d_in[1];
    float* out = (float*)d_out;

    // workspace layout (pk first for 16B alignment)
    float4* pk   = (float4*)d_ws;                      // BB*KTOP
    float* prod  = (float*)(pk + BB * KTOP);           // TOT
    float* gauss = prod + TOT;                         // TOT
    float* pmn   = gauss + TOT;                        // NBLK
    float* pmx   = pmn + NBLK;
    float* gmn   = pmx + NBLK;
    float* gmx   = gmn + NBLK;
    unsigned* bcnt  = (unsigned*)(gmx + NBLK);         // BB
    unsigned* histg = bcnt + BB;                       // BB*SELBINS
    float* candV = (float*)(histg + BB * SELBINS);     // BB*CAP
    int*   candI = (int*)(candV + BB * CAP);           // BB*CAP

    k_box9 <<<NBLK, 256, 0, stream>>>(vsm, prod, pmn, pmx, histg, bcnt);
    k_nms  <<<NBLK, 256, 0, stream>>>(vsm, prod, pmn, pmx, bcnt, candV, candI, histg);
    k_topk <<<BB, 512, 0, stream>>>(depth, bcnt, candV, candI, histg, pk);
    k_splat<<<NBLK, 256, 0, stream>>>(pk, gauss, gmn, gmx);
    k_norm <<<NBLK, 256, 0, stream>>>(gauss, gmn, gmx, out);
}

// Round 11
// 42.965 us; speedup vs baseline: 1.4400x; 1.4400x over previous
//
#include <hip/hip_runtime.h>
#include <float.h>
#include <math.h>

#define BB 8
#define HH 256
#define WW 256
#define NPIX 65536          // HH*WW
#define TOT (BB*NPIX)
#define KTOP 80
#define NTIL 64             // 8x8 tiles of 32x32 per image
#define TCAP 128            // max peaks per 32x32 tile (5x5 NMS spacing caps ~121)
#define CAP 8192            // max candidates per batch
#define SELBINS 4096
#define BNDCAP 4096
#define NBLK (BB*NTIL)      // 512
typedef unsigned long long ull;

// ============ fused 9x9 avg-pools -> prod, per-block min/max partials; zero hist+bcnt ============
__global__ void k_box9(const float* __restrict__ vsm, float* __restrict__ prod,
                       float* __restrict__ pmn, float* __restrict__ pmx,
                       unsigned* __restrict__ histg, unsigned* __restrict__ bcnt) {
    int blk = blockIdx.x;
    int b = blk >> 6, t = blk & 63;
    int ty0 = (t >> 3) << 5, tx0 = (t & 7) << 5;
    int tid = threadIdx.x;

    if (tid < 64) histg[b * SELBINS + t * 64 + tid] = 0u;
    if (blk < BB && tid == 0) bcnt[blk] = 0u;

    __shared__ float val[40][40];
    __shared__ float rs_o[40][32];
    __shared__ float rs_m[40][32];
    for (int i = tid; i < 1600; i += 256) {
        int ly = i / 40, lx = i - ly * 40;
        int gy = ty0 - 4 + ly, gx = tx0 - 4 + lx;
        float v = 0.f;
        if (gy >= 0 && gy < HH && gx >= 0 && gx < WW) v = vsm[(b * HH + gy) * WW + gx];
        val[ly][lx] = v;
    }
    __syncthreads();
    for (int i = tid; i < 1280; i += 256) {
        int ly = i >> 5, lx = i & 31;
        float so = 0.f, sm = 0.f;
        #pragma unroll
        for (int d = 0; d < 9; ++d) { float v = val[ly][lx + d]; so += (v > 0.2f) ? 1.f : 0.f; sm += v; }
        rs_o[ly][lx] = so; rs_m[ly][lx] = sm;
    }
    __syncthreads();
    int ox = tid & 31, oy0 = (tid >> 5) << 2;
    float tmn = FLT_MAX, tmx = -FLT_MAX;
    #pragma unroll
    for (int j = 0; j < 4; ++j) {
        int oy = oy0 + j;
        float so = 0.f, sm = 0.f;
        #pragma unroll
        for (int d = 0; d < 9; ++d) { so += rs_o[oy + d][ox]; sm += rs_m[oy + d][ox]; }
        float p = (so * (1.f / 81.f)) * (sm * (1.f / 81.f));
        prod[(b * HH + ty0 + oy) * WW + tx0 + ox] = p;
        tmn = fminf(tmn, p); tmx = fmaxf(tmx, p);
    }
    __shared__ float smn[256], smx[256];
    smn[tid] = tmn; smx[tid] = tmx;
    __syncthreads();
    for (int off = 128; off > 0; off >>= 1) {
        if (tid < off) { smn[tid] = fminf(smn[tid], smn[tid + off]); smx[tid] = fmaxf(smx[tid], smx[tid + off]); }
        __syncthreads();
    }
    if (tid == 0) { pmn[blk] = smn[0]; pmx[blk] = smx[0]; }
}

// ============ score + 5x5 NMS + per-BATCH compact candidates + per-batch histogram ============
__global__ void k_nms(const float* __restrict__ vsm, const float* __restrict__ prod,
                      const float* __restrict__ pmn, const float* __restrict__ pmx,
                      unsigned* __restrict__ bcnt, float* __restrict__ candV,
                      int* __restrict__ candI, unsigned* __restrict__ histg) {
    int blk = blockIdx.x;
    int b = blk >> 6, t = blk & 63;
    int ty0 = (t >> 3) << 5, tx0 = (t & 7) << 5;
    int tid = threadIdx.x;
    __shared__ float sred[2];
    if (tid < 64) {
        float mn = pmn[b * NTIL + tid];
        float mx = pmx[b * NTIL + tid];
        #pragma unroll
        for (int o = 32; o > 0; o >>= 1) { mn = fminf(mn, __shfl_xor(mn, o, 64)); mx = fmaxf(mx, __shfl_xor(mx, o, 64)); }
        if (tid == 0) { sred[0] = mn; sred[1] = mx; }
    }
    __syncthreads();
    float mnp = sred[0];
    float inv = 1.f / (sred[1] - mnp + 1e-6f);
    __shared__ float sc[36][36];
    __shared__ float hm[36][32];
    for (int i = tid; i < 1296; i += 256) {
        int ly = i / 36, lx = i - ly * 36;
        int gy = ty0 - 2 + ly, gx = tx0 - 2 + lx;
        float s = -FLT_MAX;
        if (gy >= 0 && gy < HH && gx >= 0 && gx < WW) {
            int idx = (b * HH + gy) * WW + gx;
            s = vsm[idx] * ((prod[idx] - mnp) * inv);
        }
        sc[ly][lx] = s;
    }
    __syncthreads();
    for (int i = tid; i < 1152; i += 256) {
        int ly = i >> 5, lx = i & 31;
        float m = sc[ly][lx];
        #pragma unroll
        for (int d = 1; d < 5; ++d) m = fmaxf(m, sc[ly][lx + d]);
        hm[ly][lx] = m;
    }
    __syncthreads();
    __shared__ unsigned scnt;
    __shared__ unsigned sbase;
    __shared__ float bv[TCAP];
    __shared__ int bi[TCAP];
    if (tid == 0) scnt = 0;
    __syncthreads();
    int ox = tid & 31, oy0 = (tid >> 5) << 2;
    #pragma unroll
    for (int j = 0; j < 4; ++j) {
        int oy = oy0 + j;
        float m = hm[oy][ox];
        #pragma unroll
        for (int d = 1; d < 5; ++d) m = fmaxf(m, hm[oy + d][ox]);
        float s = sc[oy + 2][ox + 2];
        if (s == m && s > 0.f) {
            unsigned p = atomicAdd(&scnt, 1u);
            if (p < TCAP) { bv[p] = s; bi[p] = (ty0 + oy) * WW + tx0 + ox; }
        }
    }
    __syncthreads();
    unsigned cnt = min(scnt, (unsigned)TCAP);
    if (tid == 0) sbase = cnt ? atomicAdd(&bcnt[b], cnt) : 0u;   // ONE global atomic per tile
    __syncthreads();
    unsigned base = sbase;
    for (unsigned i = tid; i < cnt; i += 256) {
        unsigned pos = base + i;
        if (pos < CAP) {
            float v = bv[i];
            candV[b * CAP + pos] = v;
            candI[b * CAP + pos] = bi[i];
            atomicAdd(&histg[b * SELBINS + (__float_as_uint(v) >> 19)], 1u);
        }
    }
}

// ============ exact top-80: prebuilt hist scan + unsorted accept + parallel rank-select ============
__global__ void __launch_bounds__(1024)
k_topk(const float* __restrict__ depth, const unsigned* __restrict__ bcnt,
       const float* __restrict__ candV, const int* __restrict__ candI,
       const unsigned* __restrict__ histg, float4* __restrict__ pk) {
    int b = blockIdx.x;
    int tid = threadIdx.x;
    __shared__ unsigned sc[1024];
    __shared__ ull bnd[BNDCAP];
    __shared__ ull acc[KTOP];
    __shared__ int sBin;
    __shared__ unsigned nAccS, nBndS;

    // suffix scan of prebuilt histogram (R4-proven pattern): boundary bin B
    const unsigned* hg = histg + b * SELBINS;
    int j0 = tid * 4;
    unsigned h0 = hg[j0], h1 = hg[j0 + 1], h2 = hg[j0 + 2], h3 = hg[j0 + 3];
    unsigned part = h0 + h1 + h2 + h3;
    sc[tid] = part;
    if (tid == 0) { sBin = 0; nAccS = 0; nBndS = 0; }
    __syncthreads();
    for (int off = 1; off < 1024; off <<= 1) {
        unsigned v = (tid + off < 1024) ? sc[tid + off] : 0u;
        __syncthreads();
        sc[tid] += v;
        __syncthreads();
    }
    unsigned excl = sc[tid] - part;        // suffix over threads > tid
    unsigned suf3 = excl + h3, suf2 = suf3 + h2, suf1 = suf2 + h1, suf0 = suf1 + h0;
    if (suf0 >= KTOP && suf0 - h0 < KTOP) sBin = j0;
    if (suf1 >= KTOP && suf1 - h1 < KTOP) sBin = j0 + 1;
    if (suf2 >= KTOP && suf2 - h2 < KTOP) sBin = j0 + 2;
    if (suf3 >= KTOP && suf3 - h3 < KTOP) sBin = j0 + 3;
    __syncthreads();
    int B = sBin;

    // collect from per-batch COMPACT list (~2600 entries, 3 strided rounds)
    int nC = min((int)bcnt[b], CAP);
    for (int i = tid; i < nC; i += 1024) {
        float v = candV[b * CAP + i];
        unsigned bits = __float_as_uint(v);
        int bin = (int)(bits >> 19);
        if (bin >= B) {
            ull key = ((ull)bits << 32) | (ull)(0xFFFFFFFFu - (unsigned)candI[b * CAP + i]);
            if (bin > B) {
                unsigned p = atomicAdd(&nAccS, 1u);
                if (p < KTOP) acc[p] = key;          // suffix(B+1) < 80 by scan construction
            } else {
                unsigned q = atomicAdd(&nBndS, 1u);
                if (q < BNDCAP) bnd[q] = key;
            }
        }
    }
    __syncthreads();
    unsigned nAcc = min(nAccS, (unsigned)KTOP);
    unsigned nBnd = min(nBndS, (unsigned)BNDCAP);
    unsigned quota = (KTOP > nAcc) ? (KTOP - nAcc) : 0u;
    if (quota > nBnd) quota = nBnd;

    // parallel rank-select in boundary bin: LDS broadcast reads, zero extra barriers.
    // keys are distinct (idx unique) -> ranks dense & unique -> exact top-quota set.
    for (int i = tid; i < (int)nBnd; i += 1024) {
        ull mykey = bnd[i];
        unsigned rank = 0;
        for (unsigned j = 0; j < nBnd; ++j) rank += (bnd[j] > mykey) ? 1u : 0u;
        if (rank < quota) acc[nAcc + rank] = mykey;
    }
    __syncthreads();

    // emit packed peak params {log2(val), x, y, c} (order irrelevant: splat is a max)
    if (tid < KTOP) {
        unsigned nTot = nAcc + quota;
        ull key = ((unsigned)tid < nTot) ? acc[tid] : 0ull;
        float plog = -INFINITY, fx = 0.f, fy = 0.f, c = 0.f;
        if (key) {
            unsigned bits = (unsigned)(key >> 32);
            int idx = (int)(0xFFFFFFFFu - (unsigned)(key & 0xFFFFFFFFu));
            float val = __uint_as_float(bits);
            plog = log2f(val);
            fx = (float)(idx & 255);
            fy = (float)(idx >> 8);
            float z = fmaxf(depth[b * NPIX + idx], 0.001f);
            float r = fminf(fmaxf(14.f / z, 1.5f), 18.f);
            float s2 = 0.36f * r * r;                     // (0.6*r)^2
            c = 1.44269504f / (2.f * s2 + 1e-6f);         // log2(e)/denom
        }
        pk[b * KTOP + tid] = make_float4(plog, fx, fy, c);
    }
}

// ============ log-domain gaussian splat: 4 px/thread, single exp2 per pixel ============
__global__ void k_splat(const float4* __restrict__ pk, float* __restrict__ gauss,
                        float* __restrict__ gmn, float* __restrict__ gmx) {
    int blk = blockIdx.x;
    int b = blk >> 6;
    int y0 = (blk & 63) << 2;
    int x = threadIdx.x;
    __shared__ float4 lp[KTOP];
    if (x < KTOP) lp[x] = pk[b * KTOP + x];
    __syncthreads();
    float fx = (float)x, fy = (float)y0;
    float g0 = -INFINITY, g1 = -INFINITY, g2 = -INFINITY, g3 = -INFINITY;
    #pragma unroll 4
    for (int k = 0; k < KTOP; ++k) {
        float4 q = lp[k];
        float dx = fx - q.y;
        float dx2 = dx * dx;
        float dy = fy - q.z;
        float d2;
        d2 = fmaf(dy, dy, dx2);        g0 = fmaxf(g0, fmaf(-d2, q.w, q.x));
        float dyb = dy + 1.f;
        d2 = fmaf(dyb, dyb, dx2);      g1 = fmaxf(g1, fmaf(-d2, q.w, q.x));
        float dyc = dy + 2.f;
        d2 = fmaf(dyc, dyc, dx2);      g2 = fmaxf(g2, fmaf(-d2, q.w, q.x));
        float dyd = dy + 3.f;
        d2 = fmaf(dyd, dyd, dx2);      g3 = fmaxf(g3, fmaf(-d2, q.w, q.x));
    }
    float v0 = exp2f(g0), v1 = exp2f(g1), v2 = exp2f(g2), v3 = exp2f(g3);
    int base = (b * HH + y0) * WW + x;
    gauss[base] = v0; gauss[base + WW] = v1; gauss[base + 2 * WW] = v2; gauss[base + 3 * WW] = v3;
    float tmn = fminf(fminf(v0, v1), fminf(v2, v3));
    float tmx = fmaxf(fmaxf(v0, v1), fmaxf(v2, v3));
    __shared__ float smn[256], smx[256];
    smn[x] = tmn; smx[x] = tmx;
    __syncthreads();
    for (int off = 128; off > 0; off >>= 1) {
        if (x < off) { smn[x] = fminf(smn[x], smn[x + off]); smx[x] = fmaxf(smx[x], smx[x + off]); }
        __syncthreads();
    }
    if (x == 0) { gmn[blk] = smn[0]; gmx[blk] = smx[0]; }
}

// ============ final norm01 (float4 vectorized) ============
__global__ void k_norm(const float* __restrict__ gauss, const float* __restrict__ gmn,
                       const float* __restrict__ gmx, float* __restrict__ out) {
    int blk = blockIdx.x;
    int b = blk >> 6;
    int tid = threadIdx.x;
    __shared__ float sred[2];
    if (tid < 64) {
        float mn = gmn[b * NTIL + tid];
        float mx = gmx[b * NTIL + tid];
        #pragma unroll
        for (int o = 32; o > 0; o >>= 1) { mn = fminf(mn, __shfl_xor(mn, o, 64)); mx = fmaxf(mx, __shfl_xor(mx, o, 64)); }
        if (tid == 0) { sred[0] = mn; sred[1] = mx; }
    }
    __syncthreads();
    float mn = sred[0];
    float inv = 1.f / (sred[1] - mn + 1e-6f);
    int i = blk * 256 + tid;
    float4 v = ((const float4*)gauss)[i];
    v.x = (v.x - mn) * inv;
    v.y = (v.y - mn) * inv;
    v.z = (v.z - mn) * inv;
    v.w = (v.w - mn) * inv;
    ((float4*)out)[i] = v;
}

extern "C" void kernel_launch(void* const* d_in, const int* in_sizes, int n_in,
                              void* d_out, int out_size, void* d_ws, size_t ws_size,
                              hipStream_t stream) {
    const float* vsm   = (const float*)d_in[0];
    const float* depth = (const float*)d_in[1];
    float* out = (float*)d_out;

    // workspace layout (pk first for 16B alignment)
    float4* pk   = (float4*)d_ws;                      // BB*KTOP
    float* prod  = (float*)(pk + BB * KTOP);           // TOT
    float* gauss = prod + TOT;                         // TOT
    float* pmn   = gauss + TOT;                        // NBLK
    float* pmx   = pmn + NBLK;
    float* gmn   = pmx + NBLK;
    float* gmx   = gmn + NBLK;
    unsigned* bcnt  = (unsigned*)(gmx + NBLK);         // BB
    unsigned* histg = bcnt + BB;                       // BB*SELBINS
    float* candV = (float*)(histg + BB * SELBINS);     // BB*CAP
    int*   candI = (int*)(candV + BB * CAP);           // BB*CAP

    k_box9 <<<NBLK, 256, 0, stream>>>(vsm, prod, pmn, pmx, histg, bcnt);
    k_nms  <<<NBLK, 256, 0, stream>>>(vsm, prod, pmn, pmx, bcnt, candV, candI, histg);
    k_topk <<<BB, 1024, 0, stream>>>(depth, bcnt, candV, candI, histg, pk);
    k_splat<<<NBLK, 256, 0, stream>>>(pk, gauss, gmn, gmx);
    k_norm <<<NBLK, 256, 0, stream>>>(gauss, gmn, gmx, out);
}

// Round 12
// 38.797 us; speedup vs baseline: 1.5947x; 1.1074x over previous
//
#include <hip/hip_runtime.h>
#include <float.h>
#include <math.h>

#define BB 8
#define HH 256
#define WW 256
#define NPIX 65536          // HH*WW
#define TOT (BB*NPIX)
#define KTOP 80
#define NTIL 64             // 8x8 tiles of 32x32 per image
#define TCAP 128            // max peaks per 32x32 tile (5x5 NMS spacing caps ~121)
#define CAP 8192            // max candidates per batch
#define SELBINS 4096
#define BNDCAP 4096
#define NBLK (BB*NTIL)      // 512
typedef unsigned long long ull;

// ============ fused 9x9 avg-pools -> prod, per-block min partials; zero hist+bcnt ============
__global__ void k_box9(const float* __restrict__ vsm, float* __restrict__ prod,
                       float* __restrict__ pmn,
                       unsigned* __restrict__ histg, unsigned* __restrict__ bcnt) {
    int blk = blockIdx.x;
    int b = blk >> 6, t = blk & 63;
    int ty0 = (t >> 3) << 5, tx0 = (t & 7) << 5;
    int tid = threadIdx.x;

    if (tid < 64) histg[b * SELBINS + t * 64 + tid] = 0u;
    if (blk < BB && tid == 0) bcnt[blk] = 0u;

    __shared__ float val[40][40];
    __shared__ float rs_o[40][32];
    __shared__ float rs_m[40][32];
    for (int i = tid; i < 1600; i += 256) {
        int ly = i / 40, lx = i - ly * 40;
        int gy = ty0 - 4 + ly, gx = tx0 - 4 + lx;
        float v = 0.f;
        if (gy >= 0 && gy < HH && gx >= 0 && gx < WW) v = vsm[(b * HH + gy) * WW + gx];
        val[ly][lx] = v;
    }
    __syncthreads();
    for (int i = tid; i < 1280; i += 256) {
        int ly = i >> 5, lx = i & 31;
        float so = 0.f, sm = 0.f;
        #pragma unroll
        for (int d = 0; d < 9; ++d) { float v = val[ly][lx + d]; so += (v > 0.2f) ? 1.f : 0.f; sm += v; }
        rs_o[ly][lx] = so; rs_m[ly][lx] = sm;
    }
    __syncthreads();
    int ox = tid & 31, oy0 = (tid >> 5) << 2;
    float tmn = FLT_MAX;
    #pragma unroll
    for (int j = 0; j < 4; ++j) {
        int oy = oy0 + j;
        float so = 0.f, sm = 0.f;
        #pragma unroll
        for (int d = 0; d < 9; ++d) { so += rs_o[oy + d][ox]; sm += rs_m[oy + d][ox]; }
        float p = (so * (1.f / 81.f)) * (sm * (1.f / 81.f));
        prod[(b * HH + ty0 + oy) * WW + tx0 + ox] = p;
        tmn = fminf(tmn, p);
    }
    // wave shfl min + tiny cross-wave reduce (2 barriers total in this tail)
    #pragma unroll
    for (int o = 32; o > 0; o >>= 1) tmn = fminf(tmn, __shfl_xor(tmn, o, 64));
    __shared__ float wmn[4];
    if ((tid & 63) == 0) wmn[tid >> 6] = tmn;
    __syncthreads();
    if (tid == 0) pmn[blk] = fminf(fminf(wmn[0], wmn[1]), fminf(wmn[2], wmn[3]));
}

// ============ score = vsm*(prod-mn) + 5x5 NMS + per-batch compact + histogram ============
// (the /(mx-mn+eps) scale is a per-batch positive constant: invariant through ranking,
//  bins, exp-max and the final g/vmax normalization -> dropped)
__global__ void k_nms(const float* __restrict__ vsm, const float* __restrict__ prod,
                      const float* __restrict__ pmn,
                      unsigned* __restrict__ bcnt, float* __restrict__ candV,
                      int* __restrict__ candI, unsigned* __restrict__ histg) {
    int blk = blockIdx.x;
    int b = blk >> 6, t = blk & 63;
    int ty0 = (t >> 3) << 5, tx0 = (t & 7) << 5;
    int tid = threadIdx.x;
    __shared__ float sredn;
    if (tid < 64) {
        float mn = pmn[b * NTIL + tid];
        #pragma unroll
        for (int o = 32; o > 0; o >>= 1) mn = fminf(mn, __shfl_xor(mn, o, 64));
        if (tid == 0) sredn = mn;
    }
    __syncthreads();
    float mnp = sredn;
    __shared__ float sc[36][36];
    __shared__ float hm[36][32];
    for (int i = tid; i < 1296; i += 256) {
        int ly = i / 36, lx = i - ly * 36;
        int gy = ty0 - 2 + ly, gx = tx0 - 2 + lx;
        float s = -FLT_MAX;
        if (gy >= 0 && gy < HH && gx >= 0 && gx < WW) {
            int idx = (b * HH + gy) * WW + gx;
            s = vsm[idx] * (prod[idx] - mnp);
        }
        sc[ly][lx] = s;
    }
    __syncthreads();
    for (int i = tid; i < 1152; i += 256) {
        int ly = i >> 5, lx = i & 31;
        float m = sc[ly][lx];
        #pragma unroll
        for (int d = 1; d < 5; ++d) m = fmaxf(m, sc[ly][lx + d]);
        hm[ly][lx] = m;
    }
    __syncthreads();
    __shared__ unsigned scnt;
    __shared__ unsigned sbase;
    __shared__ float bv[TCAP];
    __shared__ int bi[TCAP];
    if (tid == 0) scnt = 0;
    __syncthreads();
    int ox = tid & 31, oy0 = (tid >> 5) << 2;
    #pragma unroll
    for (int j = 0; j < 4; ++j) {
        int oy = oy0 + j;
        float m = hm[oy][ox];
        #pragma unroll
        for (int d = 1; d < 5; ++d) m = fmaxf(m, hm[oy + d][ox]);
        float s = sc[oy + 2][ox + 2];
        if (s == m && s > 0.f) {
            unsigned p = atomicAdd(&scnt, 1u);
            if (p < TCAP) { bv[p] = s; bi[p] = (ty0 + oy) * WW + tx0 + ox; }
        }
    }
    __syncthreads();
    unsigned cnt = min(scnt, (unsigned)TCAP);
    if (tid == 0) sbase = cnt ? atomicAdd(&bcnt[b], cnt) : 0u;   // ONE global atomic per tile
    __syncthreads();
    unsigned base = sbase;
    for (unsigned i = tid; i < cnt; i += 256) {
        unsigned pos = base + i;
        if (pos < CAP) {
            float v = bv[i];
            candV[b * CAP + pos] = v;
            candI[b * CAP + pos] = bi[i];
            atomicAdd(&histg[b * SELBINS + (__float_as_uint(v) >> 19)], 1u);
        }
    }
}

// ============ exact top-80: hist scan + unsorted accept + parallel rank-select; emits vmax ============
__global__ void __launch_bounds__(1024)
k_topk(const float* __restrict__ depth, const unsigned* __restrict__ bcnt,
       const float* __restrict__ candV, const int* __restrict__ candI,
       const unsigned* __restrict__ histg, float4* __restrict__ pk,
       float* __restrict__ vmaxg) {
    int b = blockIdx.x;
    int tid = threadIdx.x;
    __shared__ unsigned sc[1024];
    __shared__ ull bnd[BNDCAP];
    __shared__ ull acc[KTOP];
    __shared__ int sBin;
    __shared__ unsigned nAccS, nBndS, svm;

    const unsigned* hg = histg + b * SELBINS;
    int j0 = tid * 4;
    unsigned h0 = hg[j0], h1 = hg[j0 + 1], h2 = hg[j0 + 2], h3 = hg[j0 + 3];
    unsigned part = h0 + h1 + h2 + h3;
    sc[tid] = part;
    if (tid == 0) { sBin = 0; nAccS = 0; nBndS = 0; svm = 0; }
    __syncthreads();
    for (int off = 1; off < 1024; off <<= 1) {
        unsigned v = (tid + off < 1024) ? sc[tid + off] : 0u;
        __syncthreads();
        sc[tid] += v;
        __syncthreads();
    }
    unsigned excl = sc[tid] - part;
    unsigned suf3 = excl + h3, suf2 = suf3 + h2, suf1 = suf2 + h1, suf0 = suf1 + h0;
    if (suf0 >= KTOP && suf0 - h0 < KTOP) sBin = j0;
    if (suf1 >= KTOP && suf1 - h1 < KTOP) sBin = j0 + 1;
    if (suf2 >= KTOP && suf2 - h2 < KTOP) sBin = j0 + 2;
    if (suf3 >= KTOP && suf3 - h3 < KTOP) sBin = j0 + 3;
    __syncthreads();
    int B = sBin;

    int nC = min((int)bcnt[b], CAP);
    for (int i = tid; i < nC; i += 1024) {
        float v = candV[b * CAP + i];
        unsigned bits = __float_as_uint(v);
        int bin = (int)(bits >> 19);
        if (bin >= B) {
            ull key = ((ull)bits << 32) | (ull)(0xFFFFFFFFu - (unsigned)candI[b * CAP + i]);
            if (bin > B) {
                unsigned p = atomicAdd(&nAccS, 1u);
                if (p < KTOP) acc[p] = key;          // suffix(B+1) < 80 by scan construction
            } else {
                unsigned q = atomicAdd(&nBndS, 1u);
                if (q < BNDCAP) bnd[q] = key;
            }
        }
    }
    __syncthreads();
    unsigned nAcc = min(nAccS, (unsigned)KTOP);
    unsigned nBnd = min(nBndS, (unsigned)BNDCAP);
    unsigned quota = (KTOP > nAcc) ? (KTOP - nAcc) : 0u;
    if (quota > nBnd) quota = nBnd;

    // parallel rank-select in boundary bin (keys distinct -> dense unique ranks)
    for (int i = tid; i < (int)nBnd; i += 1024) {
        ull mykey = bnd[i];
        unsigned rank = 0;
        for (unsigned j = 0; j < nBnd; ++j) rank += (bnd[j] > mykey) ? 1u : 0u;
        if (rank < quota) acc[nAcc + rank] = mykey;
    }
    __syncthreads();

    // emit packed peak params {log2(val), x, y, c}; vmax = max accepted val (== gauss max, exact)
    unsigned nTot = nAcc + quota;
    if (tid < KTOP) {
        ull key = ((unsigned)tid < nTot) ? acc[tid] : 0ull;
        float plog = -INFINITY, fx = 0.f, fy = 0.f, c = 0.f;
        if (key) {
            unsigned bits = (unsigned)(key >> 32);
            atomicMax(&svm, bits);                        // positive floats: bit order == value order
            int idx = (int)(0xFFFFFFFFu - (unsigned)(key & 0xFFFFFFFFu));
            float val = __uint_as_float(bits);
            plog = log2f(val);
            fx = (float)(idx & 255);
            fy = (float)(idx >> 8);
            float z = fmaxf(depth[b * NPIX + idx], 0.001f);
            float r = fminf(fmaxf(14.f / z, 1.5f), 18.f);
            float s2 = 0.36f * r * r;                     // (0.6*r)^2
            c = 1.44269504f / (2.f * s2 + 1e-6f);         // log2(e)/denom
        }
        pk[b * KTOP + tid] = make_float4(plog, fx, fy, c);
    }
    __syncthreads();
    if (tid == 0) vmaxg[b] = __uint_as_float(svm);
}

// ============ log-domain splat + fused normalization (gmax = vmax exact, gmn ~ 0) ============
__global__ void __launch_bounds__(256)
k_splat(const float4* __restrict__ pk, const float* __restrict__ vmaxg,
        float* __restrict__ out) {
    int blk = blockIdx.x;
    int b = blk >> 6;
    int y0 = (blk & 63) << 2;
    int x = threadIdx.x;
    __shared__ float4 lp[KTOP];
    __shared__ float4 lpf[KTOP];
    __shared__ unsigned fcnt;
    if (x == 0) fcnt = 0;
    if (x < KTOP) lp[x] = pk[b * KTOP + x];
    __syncthreads();

    float vmax = vmaxg[b];
    float thr = log2f(vmax + 1e-30f) - 11.f;   // dropped contributions < 2^-11 * vmax

    // y-band prune: peak can matter in rows [y0, y0+3] only if plog - dymin^2*c >= thr
    if (x < KTOP) {
        float4 q = lp[x];
        float dymin = 0.f;
        if (q.z < (float)y0) dymin = (float)y0 - q.z;
        else if (q.z > (float)(y0 + 3)) dymin = q.z - (float)(y0 + 3);
        if (q.x - dymin * dymin * q.w >= thr) {
            unsigned p = atomicAdd(&fcnt, 1u);
            lpf[p] = q;
        }
    }
    __syncthreads();
    int m = (int)fcnt;

    float fx = (float)x, fy = (float)y0;
    float g0 = -INFINITY, g1 = -INFINITY, g2 = -INFINITY, g3 = -INFINITY;
    #pragma unroll 4
    for (int k = 0; k < m; ++k) {
        float4 q = lpf[k];               // {plog, px, py, c}
        float dx = fx - q.y;
        float dx2 = dx * dx;
        float dy = fy - q.z;
        float d2;
        d2 = fmaf(dy, dy, dx2);          g0 = fmaxf(g0, fmaf(-d2, q.w, q.x));
        float dyb = dy + 1.f;
        d2 = fmaf(dyb, dyb, dx2);        g1 = fmaxf(g1, fmaf(-d2, q.w, q.x));
        float dyc = dy + 2.f;
        d2 = fmaf(dyc, dyc, dx2);        g2 = fmaxf(g2, fmaf(-d2, q.w, q.x));
        float dyd = dy + 3.f;
        d2 = fmaf(dyd, dyd, dx2);        g3 = fmaxf(g3, fmaf(-d2, q.w, q.x));
    }
    float inv = 1.f / (vmax + 1e-6f);
    int base = (b * HH + y0) * WW + x;
    out[base]          = exp2f(g0) * inv;
    out[base + WW]     = exp2f(g1) * inv;
    out[base + 2 * WW] = exp2f(g2) * inv;
    out[base + 3 * WW] = exp2f(g3) * inv;
}

extern "C" void kernel_launch(void* const* d_in, const int* in_sizes, int n_in,
                              void* d_out, int out_size, void* d_ws, size_t ws_size,
                              hipStream_t stream) {
    const float* vsm   = (const float*)d_in[0];
    const float* depth = (const float*)d_in[1];
    float* out = (float*)d_out;

    // workspace layout (pk first for 16B alignment)
    float4* pk   = (float4*)d_ws;                      // BB*KTOP
    float* vmaxg = (float*)(pk + BB * KTOP);           // BB
    float* prod  = vmaxg + BB;                         // TOT
    float* pmn   = prod + TOT;                         // NBLK
    unsigned* bcnt  = (unsigned*)(pmn + NBLK);         // BB
    unsigned* histg = bcnt + BB;                       // BB*SELBINS
    float* candV = (float*)(histg + BB * SELBINS);     // BB*CAP
    int*   candI = (int*)(candV + BB * CAP);           // BB*CAP

    k_box9 <<<NBLK, 256, 0, stream>>>(vsm, prod, pmn, histg, bcnt);
    k_nms  <<<NBLK, 256, 0, stream>>>(vsm, prod, pmn, bcnt, candV, candI, histg);
    k_topk <<<BB, 1024, 0, stream>>>(depth, bcnt, candV, candI, histg, pk, vmaxg);
    k_splat<<<NBLK, 256, 0, stream>>>(pk, vmaxg, out);
}

// Round 13
// 36.282 us; speedup vs baseline: 1.7052x; 1.0693x over previous
//
#include <hip/hip_runtime.h>
#include <float.h>
#include <math.h>

#define BB 8
#define HH 256
#define WW 256
#define NPIX 65536          // HH*WW
#define TOT (BB*NPIX)
#define KTOP 80
#define NTIL 64             // 8x8 tiles of 32x32 per image
#define TCAP 128            // max peaks per 32x32 tile (5x5 NMS spacing caps ~121)
#define CAP 8192            // max candidates per batch
#define SELBINS 4096
#define BNDCAP 1024
#define NBLK (BB*NTIL)      // 512
typedef unsigned long long ull;

// ============ fused 9x9 avg-pools -> prod, per-block min partials; zero hist+bcnt ============
__global__ void k_box9(const float* __restrict__ vsm, float* __restrict__ prod,
                       float* __restrict__ pmn,
                       unsigned* __restrict__ histg, unsigned* __restrict__ bcnt) {
    int blk = blockIdx.x;
    int b = blk >> 6, t = blk & 63;
    int ty0 = (t >> 3) << 5, tx0 = (t & 7) << 5;
    int tid = threadIdx.x;

    if (tid < 64) histg[b * SELBINS + t * 64 + tid] = 0u;
    if (blk < BB && tid == 0) bcnt[blk] = 0u;

    __shared__ float val[40][40];
    __shared__ float rs_o[40][32];
    __shared__ float rs_m[40][32];
    for (int i = tid; i < 1600; i += 256) {
        int ly = i / 40, lx = i - ly * 40;
        int gy = ty0 - 4 + ly, gx = tx0 - 4 + lx;
        float v = 0.f;
        if (gy >= 0 && gy < HH && gx >= 0 && gx < WW) v = vsm[(b * HH + gy) * WW + gx];
        val[ly][lx] = v;
    }
    __syncthreads();
    for (int i = tid; i < 1280; i += 256) {
        int ly = i >> 5, lx = i & 31;
        float so = 0.f, sm = 0.f;
        #pragma unroll
        for (int d = 0; d < 9; ++d) { float v = val[ly][lx + d]; so += (v > 0.2f) ? 1.f : 0.f; sm += v; }
        rs_o[ly][lx] = so; rs_m[ly][lx] = sm;
    }
    __syncthreads();
    int ox = tid & 31, oy0 = (tid >> 5) << 2;
    float tmn = FLT_MAX;
    #pragma unroll
    for (int j = 0; j < 4; ++j) {
        int oy = oy0 + j;
        float so = 0.f, sm = 0.f;
        #pragma unroll
        for (int d = 0; d < 9; ++d) { so += rs_o[oy + d][ox]; sm += rs_m[oy + d][ox]; }
        float p = (so * (1.f / 81.f)) * (sm * (1.f / 81.f));
        prod[(b * HH + ty0 + oy) * WW + tx0 + ox] = p;
        tmn = fminf(tmn, p);
    }
    #pragma unroll
    for (int o = 32; o > 0; o >>= 1) tmn = fminf(tmn, __shfl_xor(tmn, o, 64));
    __shared__ float wmn[4];
    if ((tid & 63) == 0) wmn[tid >> 6] = tmn;
    __syncthreads();
    if (tid == 0) pmn[blk] = fminf(fminf(wmn[0], wmn[1]), fminf(wmn[2], wmn[3]));
}

// ============ score = vsm*(prod-mn) + 5x5 NMS + per-batch compact + histogram ============
__global__ void k_nms(const float* __restrict__ vsm, const float* __restrict__ prod,
                      const float* __restrict__ pmn,
                      unsigned* __restrict__ bcnt, float* __restrict__ candV,
                      int* __restrict__ candI, unsigned* __restrict__ histg) {
    int blk = blockIdx.x;
    int b = blk >> 6, t = blk & 63;
    int ty0 = (t >> 3) << 5, tx0 = (t & 7) << 5;
    int tid = threadIdx.x;
    __shared__ float sredn;
    if (tid < 64) {
        float mn = pmn[b * NTIL + tid];
        #pragma unroll
        for (int o = 32; o > 0; o >>= 1) mn = fminf(mn, __shfl_xor(mn, o, 64));
        if (tid == 0) sredn = mn;
    }
    __syncthreads();
    float mnp = sredn;
    __shared__ float sc[36][36];
    __shared__ float hm[36][32];
    for (int i = tid; i < 1296; i += 256) {
        int ly = i / 36, lx = i - ly * 36;
        int gy = ty0 - 2 + ly, gx = tx0 - 2 + lx;
        float s = -FLT_MAX;
        if (gy >= 0 && gy < HH && gx >= 0 && gx < WW) {
            int idx = (b * HH + gy) * WW + gx;
            s = vsm[idx] * (prod[idx] - mnp);
        }
        sc[ly][lx] = s;
    }
    __syncthreads();
    for (int i = tid; i < 1152; i += 256) {
        int ly = i >> 5, lx = i & 31;
        float m = sc[ly][lx];
        #pragma unroll
        for (int d = 1; d < 5; ++d) m = fmaxf(m, sc[ly][lx + d]);
        hm[ly][lx] = m;
    }
    __syncthreads();
    __shared__ unsigned scnt;
    __shared__ unsigned sbase;
    __shared__ float bv[TCAP];
    __shared__ int bi[TCAP];
    if (tid == 0) scnt = 0;
    __syncthreads();
    int ox = tid & 31, oy0 = (tid >> 5) << 2;
    #pragma unroll
    for (int j = 0; j < 4; ++j) {
        int oy = oy0 + j;
        float m = hm[oy][ox];
        #pragma unroll
        for (int d = 1; d < 5; ++d) m = fmaxf(m, hm[oy + d][ox]);
        float s = sc[oy + 2][ox + 2];
        if (s == m && s > 0.f) {
            unsigned p = atomicAdd(&scnt, 1u);
            if (p < TCAP) { bv[p] = s; bi[p] = (ty0 + oy) * WW + tx0 + ox; }
        }
    }
    __syncthreads();
    unsigned cnt = min(scnt, (unsigned)TCAP);
    if (tid == 0) sbase = cnt ? atomicAdd(&bcnt[b], cnt) : 0u;   // ONE global atomic per tile
    __syncthreads();
    unsigned base = sbase;
    for (unsigned i = tid; i < cnt; i += 256) {
        unsigned pos = base + i;
        if (pos < CAP) {
            float v = bv[i];
            candV[b * CAP + pos] = v;
            candI[b * CAP + pos] = bi[i];
            atomicAdd(&histg[b * SELBINS + (__float_as_uint(v) >> 19)], 1u);
        }
    }
}

// ============ fused: thin per-block top-80 set + log-domain splat + normalization ============
__global__ void __launch_bounds__(256)
k_tsplat(const float* __restrict__ depth, const unsigned* __restrict__ bcnt,
         const float* __restrict__ candV, const int* __restrict__ candI,
         const unsigned* __restrict__ histg, float* __restrict__ out) {
    int blk = blockIdx.x;
    int b = blk >> 6;
    int y0 = (blk & 63) << 2;
    int tid = threadIdx.x;
    int lane = tid & 63;
    int wid = tid >> 6;

    __shared__ ull acc[KTOP];
    __shared__ ull bnd[BNDCAP];
    __shared__ float4 lpf[KTOP];
    __shared__ unsigned wtot[4];
    __shared__ int sB;
    __shared__ unsigned sAbove, nAccS, nBndS, svm, fcnt;

    if (tid == 0) { sB = 0; sAbove = 0; nAccS = 0; nBndS = 0; svm = 0; fcnt = 0; }
    if (tid < KTOP) acc[tid] = 0ull;
    __syncthreads();                                       // barrier 1

    // ---- hierarchical suffix scan of prebuilt histogram (2 barriers, shfl-based) ----
    {
        const unsigned* hg = histg + b * SELBINS;
        int j0 = tid * 16;
        unsigned h[16]; unsigned part = 0;
        #pragma unroll
        for (int j = 0; j < 16; j += 4) {
            uint4 q = *reinterpret_cast<const uint4*>(hg + j0 + j);
            h[j] = q.x; h[j+1] = q.y; h[j+2] = q.z; h[j+3] = q.w;
            part += q.x + q.y + q.z + q.w;
        }
        unsigned suf = part;                               // inclusive suffix within wave
        #pragma unroll
        for (int off = 1; off < 64; off <<= 1) {
            unsigned v = __shfl_down(suf, off, 64);
            if (lane + off < 64) suf += v;
        }
        if (lane == 0) wtot[wid] = suf;                    // wave total
        __syncthreads();                                   // barrier 2
        unsigned above_waves = 0;
        #pragma unroll
        for (int w = 0; w < 4; ++w) if (w > wid) above_waves += wtot[w];
        unsigned run = above_waves + (suf - part);         // suffix over threads > tid
        for (int j = 15; j >= 0; --j) {
            unsigned hj = h[j];
            run += hj;                                     // run == suffix(j0+j)
            if (run >= KTOP && run - hj < KTOP) { sB = j0 + j; sAbove = run - hj; }
        }
        __syncthreads();                                   // barrier 3
    }
    int B = sB;

    // ---- collect from per-batch compact list: bins>B unsorted accept, bin==B staged ----
    int nC = min((int)bcnt[b], CAP);
    for (int i = tid; i < nC; i += 256) {
        float v = candV[b * CAP + i];
        unsigned bits = __float_as_uint(v);
        int bin = (int)(bits >> 19);
        if (bin >= B) {
            ull key = ((ull)bits << 32) | (ull)(0xFFFFFFFFu - (unsigned)candI[b * CAP + i]);
            atomicMax(&svm, bits);                         // vmax (positive: bit order == value order)
            if (bin > B) {
                unsigned p = atomicAdd(&nAccS, 1u);
                if (p < KTOP) acc[p] = key;                // suffix(B+1) < 80 by scan construction
            } else {
                unsigned q = atomicAdd(&nBndS, 1u);
                if (q < BNDCAP) bnd[q] = key;
            }
        }
    }
    __syncthreads();                                       // barrier 4
    unsigned nAcc = min(nAccS, (unsigned)KTOP);
    unsigned nBnd = min(nBndS, (unsigned)BNDCAP);
    unsigned quota = (KTOP > nAcc) ? (KTOP - nAcc) : 0u;
    if (quota > nBnd) quota = nBnd;

    // ---- parallel rank-select in boundary bin (LDS broadcast; keys distinct -> exact set) ----
    for (int i = tid; i < (int)nBnd; i += 256) {
        ull mykey = bnd[i];
        unsigned rank = 0;
        for (unsigned j = 0; j < nBnd; ++j) rank += (bnd[j] > mykey) ? 1u : 0u;
        if (rank < quota) acc[nAcc + rank] = mykey;
    }
    __syncthreads();                                       // barrier 5

    // ---- peak params + y-band prune into lpf ----
    float vmax = __uint_as_float(svm);
    float thr = log2f(vmax + 1e-30f) - 11.f;               // drop contributions < 2^-11 * vmax
    unsigned nTot = nAcc + quota;
    if (tid < (int)nTot) {
        ull key = acc[tid];
        if (key) {
            unsigned bits = (unsigned)(key >> 32);
            int idx = (int)(0xFFFFFFFFu - (unsigned)(key & 0xFFFFFFFFu));
            float val = __uint_as_float(bits);
            float plog = log2f(val);
            float fy = (float)(idx >> 8);
            float z = fmaxf(depth[b * NPIX + idx], 0.001f);
            float r = fminf(fmaxf(14.f / z, 1.5f), 18.f);
            float s2 = 0.36f * r * r;                      // (0.6*r)^2
            float c = 1.44269504f / (2.f * s2 + 1e-6f);    // log2(e)/denom
            float dymin = 0.f;
            if (fy < (float)y0) dymin = (float)y0 - fy;
            else if (fy > (float)(y0 + 3)) dymin = fy - (float)(y0 + 3);
            if (plog - dymin * dymin * c >= thr) {
                unsigned p = atomicAdd(&fcnt, 1u);
                lpf[p] = make_float4(plog, (float)(idx & 255), fy, c);
            }
        }
    }
    __syncthreads();                                       // barrier 6
    int m = (int)fcnt;

    // ---- log-domain splat, 4 rows/block, fused 1/vmax normalization ----
    float fx = (float)tid, fyv = (float)y0;
    float g0 = -INFINITY, g1 = -INFINITY, g2 = -INFINITY, g3 = -INFINITY;
    #pragma unroll 4
    for (int k = 0; k < m; ++k) {
        float4 q = lpf[k];                   // {plog, px, py, c}
        float dx = fx - q.y;
        float dx2 = dx * dx;
        float dy = fyv - q.z;
        float d2;
        d2 = fmaf(dy, dy, dx2);              g0 = fmaxf(g0, fmaf(-d2, q.w, q.x));
        float dyb = dy + 1.f;
        d2 = fmaf(dyb, dyb, dx2);            g1 = fmaxf(g1, fmaf(-d2, q.w, q.x));
        float dyc = dy + 2.f;
        d2 = fmaf(dyc, dyc, dx2);            g2 = fmaxf(g2, fmaf(-d2, q.w, q.x));
        float dyd = dy + 3.f;
        d2 = fmaf(dyd, dyd, dx2);            g3 = fmaxf(g3, fmaf(-d2, q.w, q.x));
    }
    float inv = 1.f / (vmax + 1e-6f);
    int base = (b * HH + y0) * WW + tid;
    out[base]          = exp2f(g0) * inv;
    out[base + WW]     = exp2f(g1) * inv;
    out[base + 2 * WW] = exp2f(g2) * inv;
    out[base + 3 * WW] = exp2f(g3) * inv;
}

extern "C" void kernel_launch(void* const* d_in, const int* in_sizes, int n_in,
                              void* d_out, int out_size, void* d_ws, size_t ws_size,
                              hipStream_t stream) {
    const float* vsm   = (const float*)d_in[0];
    const float* depth = (const float*)d_in[1];
    float* out = (float*)d_out;

    // workspace layout
    float* prod  = (float*)d_ws;                       // TOT
    float* pmn   = prod + TOT;                         // NBLK
    unsigned* bcnt  = (unsigned*)(pmn + NBLK);         // BB
    unsigned* histg = bcnt + BB;                       // BB*SELBINS
    float* candV = (float*)(histg + BB * SELBINS);     // BB*CAP
    int*   candI = (int*)(candV + BB * CAP);           // BB*CAP

    k_box9  <<<NBLK, 256, 0, stream>>>(vsm, prod, pmn, histg, bcnt);
    k_nms   <<<NBLK, 256, 0, stream>>>(vsm, prod, pmn, bcnt, candV, candI, histg);
    k_tsplat<<<NBLK, 256, 0, stream>>>(depth, bcnt, candV, candI, histg, out);
}